// Round 10
// baseline (804.643 us; speedup 1.0000x reference)
//
#include <hip/hip_runtime.h>
#include <cstdint>
#include <cstddef>

#define NPTS   4096
#define BATCH  4
#define KNN    8
#define EPS_F  1e-12f
#define NBLK2  ((BATCH * NPTS) / 64)   // 256 loss blocks

// Spatial grid: 32^3 cells of h=0.3125 over [-5,5]^3 (N(0,1) data:
// densest cell ~8 pts; P(|coord|>5) ~ 6e-7 -> clamped to edge cells).
#define G      32
#define NC3    (G * G * G)     // 32768 cells
#define CAP    24              // slots/cell; P(Poisson(8) > 24) ~ 3e-7
#define GLO    -5.0f
#define GH     0.3125f         // 5/16, exact in fp32
#define GINV   3.2f

__device__ __forceinline__ uint32_t u32min(uint32_t a, uint32_t b) { return a < b ? a : b; }
__device__ __forceinline__ uint32_t u32max(uint32_t a, uint32_t b) { return a > b ? a : b; }

// v_med3_u32: for sorted a<=b, med3(a,b,x) == clamp(x,a,b) — one instruction.
__device__ __forceinline__ uint32_t umed3(uint32_t a, uint32_t b, uint32_t c) {
  uint32_t d;
  asm("v_med3_u32 %0, %1, %2, %3" : "=v"(d) : "v"(a), "v"(b), "v"(c));
  return d;
}

// Insert key into ascending D-list, dropping the largest: 1 min + (D-1) med3.
template <int D>
__device__ __forceinline__ void insertD(uint32_t (&loc)[D], uint32_t key) {
  uint32_t prev = loc[0];
  loc[0] = u32min(prev, key);
#pragma unroll
  for (int m = 1; m < D; ++m) {
    const uint32_t cur = loc[m];
    loc[m] = umed3(prev, cur, key);
    prev = cur;
  }
}

__device__ __forceinline__ int cell1d(float x) {
  int c = (int)floorf((x - GLO) * GINV);
  return c < 0 ? 0 : (c > G - 1 ? G - 1 : c);
}

// ---------------------------------------------------------------------------
// zero_k: clear cell counters (1 MB) + ticket. Runs every launch, so graph
// replays over a poisoned/stale workspace always start from clean counts.
// ---------------------------------------------------------------------------
__global__ void __launch_bounds__(256)
zero_k(uint32_t* __restrict__ cnt, uint32_t* __restrict__ ticket) {
  const int t = blockIdx.x * 256 + threadIdx.x;      // 0..65535
  ((uint4*)cnt)[t] = make_uint4(0u, 0u, 0u, 0u);     // 65536 x 16 B = 1 MB
  if (t == 0) *ticket = 0u;
}

// ---------------------------------------------------------------------------
// count_k: bucket each point into its cell (atomic slot; u16 index list).
// Insertion-slot order is nondeterministic but the selection key order is
// strict (truncated-d2, j) -> final result order-independent.
// ---------------------------------------------------------------------------
__global__ void __launch_bounds__(256)
count_k(const float* __restrict__ pred, const float* __restrict__ tgt,
        uint32_t* __restrict__ cnt, uint16_t* __restrict__ lst) {
  const int t = blockIdx.x * 256 + threadIdx.x;      // 0..32767
  const int set = t >> 12, j = t & (NPTS - 1);
  const float* pts = ((set >> 2) ? tgt : pred) + (size_t)(set & 3) * NPTS * 3;
  const float x = pts[3 * j], y = pts[3 * j + 1], z = pts[3 * j + 2];
  const int cid = (cell1d(x) << 10) | (cell1d(y) << 5) | cell1d(z);
  const uint32_t base = (uint32_t)set * NC3 + (uint32_t)cid;
  const uint32_t slot = atomicAdd(&cnt[base], 1u);
  if (slot < CAP) lst[(size_t)base * CAP + slot] = (uint16_t)j;
}

// ---------------------------------------------------------------------------
// scan_k: per point, exact pruned kNN top-8.
// Scan the L=1 cell box, then expand shells while the provable coverage
// radius g (min distance from p to an unscanned box face; clamped face =
// inf) is below the 8th key's bucket-upper-bound. Any unscanned point is
// beyond some face -> d >= g, so d8_true <= d8_upper <= g guarantees
// exactness. Key/truncation/tie semantics identical to the proven kernels;
// depth-8 per point (coverage strictly >= the old SD=3-per-chunk scheme).
// Loop hard-capped at L < G (termination guaranteed even for bad inputs).
// ---------------------------------------------------------------------------
__global__ void __launch_bounds__(256, 4)
scan_k(const float* __restrict__ pred, const float* __restrict__ tgt,
       const uint32_t* __restrict__ cnt, const uint16_t* __restrict__ lst,
       uint32_t* __restrict__ fin) {
  const int t = blockIdx.x * 256 + threadIdx.x;      // 0..32767
  const int set = t >> 12, i = t & (NPTS - 1);
  const float* __restrict__ pts = ((set >> 2) ? tgt : pred) + (size_t)(set & 3) * NPTS * 3;
  const float px = pts[3 * i], py = pts[3 * i + 1], pz = pts[3 * i + 2];
  const int cx = cell1d(px), cy = cell1d(py), cz = cell1d(pz);

  const uint32_t* __restrict__ C = cnt + (size_t)set * NC3;
  const uint16_t* __restrict__ LL = lst + (size_t)set * NC3 * CAP;

  uint32_t loc[KNN];
#pragma unroll
  for (int k = 0; k < KNN; ++k) loc[k] = 0xFFFFFFFFu;

#define SCAN_CELL(X, Y, Z)                                                     \
  {                                                                            \
    const int cid_ = ((X) << 10) | ((Y) << 5) | (Z);                           \
    const int n_ = (int)u32min(C[cid_], (uint32_t)CAP);                        \
    const uint32_t b_ = (uint32_t)cid_ * CAP;                                  \
    for (int k_ = 0; k_ < n_; ++k_) {                                          \
      const int j_ = (int)LL[b_ + k_];                                         \
      const float dx_ = px - pts[3 * j_ + 0];                                  \
      const float dy_ = py - pts[3 * j_ + 1];                                  \
      const float dz_ = pz - pts[3 * j_ + 2];                                  \
      const float d2_ = fmaf(dx_, dx_, fmaf(dy_, dy_, dz_ * dz_));             \
      uint32_t key_ = (__float_as_uint(d2_) & 0xFFFFF000u) | (uint32_t)j_;     \
      key_ = (j_ == i) ? 0xFFFFFFFFu : key_;                                   \
      insertD<KNN>(loc, key_);                                                 \
    }                                                                          \
  }

  // L=1 box
  {
    const int xlo = cx > 0 ? cx - 1 : 0, xhi = cx < G - 1 ? cx + 1 : G - 1;
    const int ylo = cy > 0 ? cy - 1 : 0, yhi = cy < G - 1 ? cy + 1 : G - 1;
    const int zlo = cz > 0 ? cz - 1 : 0, zhi = cz < G - 1 ? cz + 1 : G - 1;
    for (int X = xlo; X <= xhi; ++X)
      for (int Y = ylo; Y <= yhi; ++Y)
        for (int Z = zlo; Z <= zhi; ++Z)
          SCAN_CELL(X, Y, Z)
  }

  int L = 1;
  while (L < G) {
    // coverage guarantee for the scanned box [c-L, c+L]^3 (clamped = inf)
    const float glx = (cx - L <= 0)     ? 1e30f : px - (GLO + (float)(cx - L) * GH);
    const float ghx = (cx + L >= G - 1) ? 1e30f : (GLO + (float)(cx + L + 1) * GH) - px;
    const float gly = (cy - L <= 0)     ? 1e30f : py - (GLO + (float)(cy - L) * GH);
    const float ghy = (cy + L >= G - 1) ? 1e30f : (GLO + (float)(cy + L + 1) * GH) - py;
    const float glz = (cz - L <= 0)     ? 1e30f : pz - (GLO + (float)(cz - L) * GH);
    const float ghz = (cz + L >= G - 1) ? 1e30f : (GLO + (float)(cz + L + 1) * GH) - pz;
    const float g = fminf(fminf(fminf(glx, ghx), fminf(gly, ghy)), fminf(glz, ghz));
    const float g2 = g * g;
    const bool have8 = (loc[KNN - 1] != 0xFFFFFFFFu);
    const float d8u = __uint_as_float((loc[KNN - 1] & 0xFFFFF000u) + 0x1000u);
    if (have8 && d8u <= g2) break;
    const bool allx = (cx - L <= 0) && (cx + L >= G - 1);
    const bool ally = (cy - L <= 0) && (cy + L >= G - 1);
    const bool allz = (cz - L <= 0) && (cz + L >= G - 1);
    if (allx && ally && allz) break;   // whole grid scanned
    ++L;
    // shell: Chebyshev distance exactly L
    const int xlo = cx - L > 0 ? cx - L : 0, xhi = cx + L < G - 1 ? cx + L : G - 1;
    const int ylo = cy - L > 0 ? cy - L : 0, yhi = cy + L < G - 1 ? cy + L : G - 1;
    for (int X = xlo; X <= xhi; ++X) {
      const bool xedge = (X == cx - L) || (X == cx + L);
      for (int Y = ylo; Y <= yhi; ++Y) {
        const bool yedge = (Y == cy - L) || (Y == cy + L);
        if (xedge || yedge) {
          const int zlo = cz - L > 0 ? cz - L : 0, zhi = cz + L < G - 1 ? cz + L : G - 1;
          for (int Z = zlo; Z <= zhi; ++Z) SCAN_CELL(X, Y, Z)
        } else {
          const int zm = cz - L, zp = cz + L;
          if (zm >= 0)     SCAN_CELL(X, Y, zm)
          if (zp <= G - 1) SCAN_CELL(X, Y, zp)
        }
      }
    }
  }
#undef SCAN_CELL

  uint4* fp = (uint4*)(fin + ((size_t)set * NPTS + (size_t)i) * 8);
  fp[0] = make_uint4(loc[0], loc[1], loc[2], loc[3]);
  fp[1] = make_uint4(loc[4], loc[5], loc[6], loc[7]);
}

// Per-cloud: coord gather (8 independent loads), density/cov/unit vectors.
// Indices in the low 12 bits of the key (j < 4096).
__device__ __forceinline__ void cloud_stats(const float* __restrict__ C, int i,
                                            const uint32_t v[KNN],
                                            float& dsum, float cov[6],
                                            float nx[KNN], float ny[KNN], float nz[KNN]) {
  const float qx = C[3 * i], qy = C[3 * i + 1], qz = C[3 * i + 2];
  float jx[KNN], jy[KNN], jz[KNN];
#pragma unroll
  for (int k = 0; k < KNN; ++k) {
    const int j = (int)(v[k] & 0xFFFu);
    jx[k] = C[3 * j]; jy[k] = C[3 * j + 1]; jz[k] = C[3 * j + 2];
  }
  dsum = 0.f;
#pragma unroll
  for (int m = 0; m < 6; ++m) cov[m] = 0.f;
#pragma unroll
  for (int k = 0; k < KNN; ++k) {
    const float ax = jx[k] - qx, ay = jy[k] - qy, az = jz[k] - qz;
    const float d2 = fmaf(ax, ax, fmaf(ay, ay, az * az));
    const float dist = sqrtf(fmaxf(d2, EPS_F));
    const float inv = 1.0f / fmaxf(dist, EPS_F);
    dsum += dist;
    cov[0] += ax * ax; cov[1] += ay * ay; cov[2] += az * az;
    cov[3] += ax * ay; cov[4] += ax * az; cov[5] += ay * az;
    nx[k] = ax * inv; ny[k] = ay * inv; nz[k] = az * inv;
  }
}

// ---------------------------------------------------------------------------
// loss_k — proven stats/reduction path; merge network replaced by direct
// loads of the per-point top-8 from scan_k.
// ---------------------------------------------------------------------------
__global__ void __launch_bounds__(64, 1)
loss_k(const float* __restrict__ pred, const float* __restrict__ tgt,
       const uint32_t* __restrict__ fin, double* __restrict__ bsum,
       uint32_t* __restrict__ ticket, float* __restrict__ out) {
  const int p = blockIdx.x * 64 + threadIdx.x;   // 0 .. 16383
  const int b = p >> 12;
  const int i = p & (NPTS - 1);

  const float* __restrict__ P = pred + (size_t)b * NPTS * 3;
  const float* __restrict__ T = tgt  + (size_t)b * NPTS * 3;

  uint32_t vp[KNN], vt[KNN];
  {
    const uint4* fp = (const uint4*)(fin + ((size_t)b * NPTS + (size_t)i) * 8);
    const uint4 a0 = fp[0], a1 = fp[1];
    vp[0] = a0.x; vp[1] = a0.y; vp[2] = a0.z; vp[3] = a0.w;
    vp[4] = a1.x; vp[5] = a1.y; vp[6] = a1.z; vp[7] = a1.w;
    const uint4* ft = (const uint4*)(fin + ((size_t)(BATCH + b) * NPTS + (size_t)i) * 8);
    const uint4 b0 = ft[0], b1 = ft[1];
    vt[0] = b0.x; vt[1] = b0.y; vt[2] = b0.z; vt[3] = b0.w;
    vt[4] = b1.x; vt[5] = b1.y; vt[6] = b1.z; vt[7] = b1.w;
  }

  float dsp, dst, pcov[6], tcov[6];
  float pnx[KNN], pny[KNN], pnz[KNN], tnx[KNN], tny[KNN], tnz[KNN];
  cloud_stats(P, i, vp, dsp, pcov, pnx, pny, pnz);
  cloud_stats(T, i, vt, dst, tcov, tnx, tny, tnz);

  float sdot = 0.f;
#pragma unroll
  for (int k = 0; k < KNN; ++k)
    sdot += pnx[k] * tnx[k] + pny[k] * tny[k] + pnz[k] * tnz[k];

  const float densp = dsp * (1.0f / KNN);
  const float denst = dst * (1.0f / KNN);
  float e = (densp - denst) * (densp - denst);

  const float dxx = (pcov[0] - tcov[0]) * (1.0f / KNN);
  const float dyy = (pcov[1] - tcov[1]) * (1.0f / KNN);
  const float dzz = (pcov[2] - tcov[2]) * (1.0f / KNN);
  const float dxy = (pcov[3] - tcov[3]) * (1.0f / KNN);
  const float dxz = (pcov[4] - tcov[4]) * (1.0f / KNN);
  const float dyz = (pcov[5] - tcov[5]) * (1.0f / KNN);
  float cfro = sqrtf(dxx * dxx + dyy * dyy + dzz * dzz
                     + 2.0f * (dxy * dxy + dxz * dxz + dyz * dyz));
  float s = sdot;

#pragma unroll
  for (int off = 32; off > 0; off >>= 1) {
    e    += __shfl_down(e, off);
    s    += __shfl_down(s, off);
    cfro += __shfl_down(cfro, off);
  }

  unsigned rank = 0u;
  if (threadIdx.x == 0) {
    double* d = bsum + 3 * (size_t)blockIdx.x;
    d[0] = (double)e; d[1] = (double)s; d[2] = (double)cfro;
    __threadfence();                       // release
    rank = atomicAdd(ticket, 1u) + 1u;
  }
  rank = __shfl(rank, 0);
  if (rank == (unsigned)NBLK2) {           // last block: whole wave reduces
    __threadfence();                       // acquire
    double ee = 0.0, ss = 0.0, cc = 0.0;
#pragma unroll
    for (int g = 0; g < NBLK2 / 64; ++g) {
      double* d = bsum + 3 * (size_t)(threadIdx.x + 64 * g);
      ee += __hip_atomic_load(&d[0], __ATOMIC_RELAXED, __HIP_MEMORY_SCOPE_AGENT);
      ss += __hip_atomic_load(&d[1], __ATOMIC_RELAXED, __HIP_MEMORY_SCOPE_AGENT);
      cc += __hip_atomic_load(&d[2], __ATOMIC_RELAXED, __HIP_MEMORY_SCOPE_AGENT);
    }
#pragma unroll
    for (int off = 32; off > 0; off >>= 1) {
      ee += __shfl_down(ee, off);
      ss += __shfl_down(ss, off);
      cc += __shfl_down(cc, off);
    }
    if (threadIdx.x == 0) {
      const double BN = (double)BATCH * (double)NPTS;
      out[0] = (float)(ee / BN + 0.5 * (1.0 - ss / (BN * (double)KNN)) + 0.5 * (cc / BN));
    }
  }
}

extern "C" void kernel_launch(void* const* d_in, const int* in_sizes, int n_in,
                              void* d_out, int out_size, void* d_ws, size_t ws_size,
                              hipStream_t stream) {
  const float* pred = (const float*)d_in[0];
  const float* tgt  = (const float*)d_in[1];
  uint32_t* ticket = (uint32_t*)((char*)d_ws + 64);
  double*   bsum   = (double*)((char*)d_ws + 4096);            // 256 x 3 doubles
  uint32_t* fin    = (uint32_t*)((char*)d_ws + 65536);         // 1 MB  (8 sets x 4096 x 8 u32)
  uint32_t* cnt    = (uint32_t*)((char*)d_ws + (2u << 20));    // 1 MB  (8 x 32768 u32)
  uint16_t* lst    = (uint16_t*)((char*)d_ws + (4u << 20));    // 12.6 MB (8 x 32768 x 24 u16)

  zero_k<<<256, 256, 0, stream>>>(cnt, ticket);
  count_k<<<(2 * BATCH * NPTS) / 256, 256, 0, stream>>>(pred, tgt, cnt, lst);
  scan_k<<<(2 * BATCH * NPTS) / 256, 256, 0, stream>>>(pred, tgt, cnt, lst, fin);
  loss_k<<<NBLK2, 64, 0, stream>>>(pred, tgt, fin, bsum, ticket, (float*)d_out);
}

// Round 11
// 430.111 us; speedup vs baseline: 1.8708x; 1.8708x over previous
//
#include <hip/hip_runtime.h>
#include <cstdint>
#include <cstddef>

#define NPTS   4096
#define BATCH  4
#define NSET   (2 * BATCH)     // 8 point sets (2 clouds x 4 batches)
#define KNN    8
#define EPS_F  1e-12f
#define NBLK2  ((BATCH * NPTS) / 64)   // 256 loss blocks

// Spatial grid: 32^3 cells of h=0.3125 over [-5,5]^3 (N(0,1) data:
// densest cell ~8 pts; P(|coord|>5) ~ 6e-7 -> clamped to edge cells).
#define G      32
#define NC3    (G * G * G)     // 32768 cells
#define GLO    -5.0f
#define GH     0.3125f         // 5/16, exact in fp32
#define GINV   3.2f

__device__ __forceinline__ uint32_t u32min(uint32_t a, uint32_t b) { return a < b ? a : b; }

// v_med3_u32: for sorted a<=b, med3(a,b,x) == clamp(x,a,b) — one instruction.
__device__ __forceinline__ uint32_t umed3(uint32_t a, uint32_t b, uint32_t c) {
  uint32_t d;
  asm("v_med3_u32 %0, %1, %2, %3" : "=v"(d) : "v"(a), "v"(b), "v"(c));
  return d;
}

// Insert key into ascending D-list, dropping the largest: 1 min + (D-1) med3.
template <int D>
__device__ __forceinline__ void insertD(uint32_t (&loc)[D], uint32_t key) {
  uint32_t prev = loc[0];
  loc[0] = u32min(prev, key);
#pragma unroll
  for (int m = 1; m < D; ++m) {
    const uint32_t cur = loc[m];
    loc[m] = umed3(prev, cur, key);
    prev = cur;
  }
}

__device__ __forceinline__ int cell1d(float x) {
  int c = (int)floorf((x - GLO) * GINV);
  return c < 0 ? 0 : (c > G - 1 ? G - 1 : c);
}

// ---------------------------------------------------------------------------
// zero_k: clear cell counters (1 MB) + ticket. Runs every launch (re-poison
// safe: graph replays always start from clean counts).
// ---------------------------------------------------------------------------
__global__ void __launch_bounds__(256)
zero_k(uint32_t* __restrict__ cnt, uint32_t* __restrict__ ticket) {
  const int t = blockIdx.x * 256 + threadIdx.x;      // 0..65535
  ((uint4*)cnt)[t] = make_uint4(0u, 0u, 0u, 0u);     // NSET*NC3 u32 = 1 MB
  if (t == 0) *ticket = 0u;
}

// ---------------------------------------------------------------------------
// count_k: per point, atomically grab a slot in its cell; record (cid, slot).
// Slot order is nondeterministic; selection is order-independent (strict
// truncated-d2|j key order), so the final result is deterministic.
// ---------------------------------------------------------------------------
__global__ void __launch_bounds__(256)
count_k(const float* __restrict__ pred, const float* __restrict__ tgt,
        uint32_t* __restrict__ cnt, uint32_t* __restrict__ pcs) {
  const int t = blockIdx.x * 256 + threadIdx.x;      // 0..32767
  const int set = t >> 12, j = t & (NPTS - 1);
  const float* pts = ((set >> 2) ? tgt : pred) + (size_t)(set & 3) * NPTS * 3;
  const float x = pts[3 * j], y = pts[3 * j + 1], z = pts[3 * j + 2];
  const int cid = (cell1d(x) << 10) | (cell1d(y) << 5) | cell1d(z);
  const uint32_t slot = atomicAdd(&cnt[(size_t)set * NC3 + cid], 1u);
  pcs[t] = (uint32_t)cid | (slot << 16);
}

// ---------------------------------------------------------------------------
// offsets_k: exclusive prefix sum cnt -> off, one block per set.
// 1024 threads x 32 cells each; LDS Hillis-Steele over the 1024 partials.
// ---------------------------------------------------------------------------
__global__ void __launch_bounds__(1024)
offsets_k(const uint32_t* __restrict__ cnt, uint32_t* __restrict__ off) {
  __shared__ uint32_t sbuf[1024];
  const int set = blockIdx.x, t = threadIdx.x;
  const uint32_t* C = cnt + (size_t)set * NC3 + t * 32;
  uint32_t c[32];
  uint32_t sum = 0;
#pragma unroll
  for (int k = 0; k < 32; ++k) { c[k] = C[k]; sum += c[k]; }
  const uint32_t mysum = sum;
  sbuf[t] = sum;
  __syncthreads();
#pragma unroll
  for (int d = 1; d < 1024; d <<= 1) {
    const uint32_t v = (t >= d) ? sbuf[t - d] : 0u;
    __syncthreads();
    sbuf[t] += v;
    __syncthreads();
  }
  uint32_t run = sbuf[t] - mysum;          // exclusive offset of this thread
  uint32_t* O = off + (size_t)set * NC3 + t * 32;
#pragma unroll
  for (int k = 0; k < 32; ++k) { O[k] = run; run += c[k]; }
}

// ---------------------------------------------------------------------------
// scatter_k: write each point as float4(x,y,z, bitcast j) into cell-sorted
// CSR order: pos = off[cid] + slot.
// ---------------------------------------------------------------------------
__global__ void __launch_bounds__(256)
scatter_k(const float* __restrict__ pred, const float* __restrict__ tgt,
          const uint32_t* __restrict__ off, const uint32_t* __restrict__ pcs,
          float4* __restrict__ srt) {
  const int t = blockIdx.x * 256 + threadIdx.x;      // 0..32767
  const int set = t >> 12, j = t & (NPTS - 1);
  const float* pts = ((set >> 2) ? tgt : pred) + (size_t)(set & 3) * NPTS * 3;
  const uint32_t cs = pcs[t];
  const uint32_t cid = cs & 0xFFFFu, slot = cs >> 16;
  const uint32_t pos = off[(size_t)set * NC3 + cid] + slot;
  srt[(size_t)set * NPTS + pos] =
      make_float4(pts[3 * j], pts[3 * j + 1], pts[3 * j + 2], __uint_as_float((uint32_t)j));
}

// ---------------------------------------------------------------------------
// scan_k: exact pruned kNN top-8, processed in CELL-SORTED RANK order —
// the 64 lanes of a wave are spatial neighbors: same cells, same loop
// counts (convergent exec), shared cache lines. Cells along z are cid-
// contiguous, so each (X,Y) row of the search box is ONE contiguous CSR
// segment of float4s (coalesced stream, no index indirection).
// Shell expansion + provable face-distance guarantee (clamped face = inf)
// => exact under the same key semantics as all proven rounds.
// ---------------------------------------------------------------------------
__global__ void __launch_bounds__(64)
scan_k(const float4* __restrict__ srt, const uint32_t* __restrict__ cnt,
       const uint32_t* __restrict__ off, uint32_t* __restrict__ fin) {
  const int t = blockIdx.x * 64 + threadIdx.x;       // 0..32767
  const int set = t >> 12, r = t & (NPTS - 1);       // r = sorted rank
  const float4* __restrict__ S = srt + (size_t)set * NPTS;
  const uint32_t* __restrict__ C = cnt + (size_t)set * NC3;
  const uint32_t* __restrict__ O = off + (size_t)set * NC3;

  const float4 q = S[r];
  const float px = q.x, py = q.y, pz = q.z;
  const uint32_t iq = __float_as_uint(q.w);          // original index
  const int cx = cell1d(px), cy = cell1d(py), cz = cell1d(pz);

  uint32_t loc[KNN];
#pragma unroll
  for (int k = 0; k < KNN; ++k) loc[k] = 0xFFFFFFFFu;

#define SCAN_SEG(S_, E_)                                                       \
  for (uint32_t p_ = (S_); p_ < (E_); ++p_) {                                  \
    const float4 c_ = S[p_];                                                   \
    const float dx_ = px - c_.x, dy_ = py - c_.y, dz_ = pz - c_.z;             \
    const float d2_ = fmaf(dx_, dx_, fmaf(dy_, dy_, dz_ * dz_));               \
    const uint32_t j_ = __float_as_uint(c_.w);                                 \
    uint32_t key_ = (__float_as_uint(d2_) & 0xFFFFF000u) | j_;                 \
    key_ = (j_ == iq) ? 0xFFFFFFFFu : key_;                                    \
    insertD<KNN>(loc, key_);                                                   \
  }

#define ZROW(X, Y, ZLO, ZHI)                                                   \
  {                                                                            \
    const int clo_ = ((X) << 10) | ((Y) << 5) | (ZLO);                         \
    const int chi_ = ((X) << 10) | ((Y) << 5) | (ZHI);                         \
    const uint32_t s_ = O[clo_];                                               \
    const uint32_t e_ = O[chi_] + C[chi_];                                     \
    SCAN_SEG(s_, e_)                                                           \
  }

  // L=1 box: rows of contiguous z-cells.
  {
    const int xlo = cx > 0 ? cx - 1 : 0, xhi = cx < G - 1 ? cx + 1 : G - 1;
    const int ylo = cy > 0 ? cy - 1 : 0, yhi = cy < G - 1 ? cy + 1 : G - 1;
    const int zlo = cz > 0 ? cz - 1 : 0, zhi = cz < G - 1 ? cz + 1 : G - 1;
    for (int X = xlo; X <= xhi; ++X)
      for (int Y = ylo; Y <= yhi; ++Y)
        ZROW(X, Y, zlo, zhi)
  }

  int L = 1;
  while (L < G) {
    // coverage guarantee for the scanned box [c-L, c+L]^3 (clamped = inf)
    const float glx = (cx - L <= 0)     ? 1e30f : px - (GLO + (float)(cx - L) * GH);
    const float ghx = (cx + L >= G - 1) ? 1e30f : (GLO + (float)(cx + L + 1) * GH) - px;
    const float gly = (cy - L <= 0)     ? 1e30f : py - (GLO + (float)(cy - L) * GH);
    const float ghy = (cy + L >= G - 1) ? 1e30f : (GLO + (float)(cy + L + 1) * GH) - py;
    const float glz = (cz - L <= 0)     ? 1e30f : pz - (GLO + (float)(cz - L) * GH);
    const float ghz = (cz + L >= G - 1) ? 1e30f : (GLO + (float)(cz + L + 1) * GH) - pz;
    const float g = fminf(fminf(fminf(glx, ghx), fminf(gly, ghy)), fminf(glz, ghz));
    const float g2 = g * g;
    const bool have8 = (loc[KNN - 1] != 0xFFFFFFFFu);
    const float d8u = __uint_as_float((loc[KNN - 1] & 0xFFFFF000u) + 0x1000u);
    if (have8 && d8u <= g2) break;
    const bool allx = (cx - L <= 0) && (cx + L >= G - 1);
    const bool ally = (cy - L <= 0) && (cy + L >= G - 1);
    const bool allz = (cz - L <= 0) && (cz + L >= G - 1);
    if (allx && ally && allz) break;   // whole grid scanned
    ++L;
    // shell: Chebyshev distance exactly L
    const int xlo = cx - L > 0 ? cx - L : 0, xhi = cx + L < G - 1 ? cx + L : G - 1;
    const int ylo = cy - L > 0 ? cy - L : 0, yhi = cy + L < G - 1 ? cy + L : G - 1;
    const int zlo = cz - L > 0 ? cz - L : 0, zhi = cz + L < G - 1 ? cz + L : G - 1;
    for (int X = xlo; X <= xhi; ++X) {
      const bool xedge = (X == cx - L) || (X == cx + L);
      for (int Y = ylo; Y <= yhi; ++Y) {
        const bool yedge = (Y == cy - L) || (Y == cy + L);
        if (xedge || yedge) {
          ZROW(X, Y, zlo, zhi)
        } else {
          const int zm = cz - L, zp = cz + L;
          if (zm >= 0)     ZROW(X, Y, zm, zm)
          if (zp <= G - 1) ZROW(X, Y, zp, zp)
        }
      }
    }
  }
#undef ZROW
#undef SCAN_SEG

  uint4* fp = (uint4*)(fin + ((size_t)set * NPTS + (size_t)iq) * 8);
  fp[0] = make_uint4(loc[0], loc[1], loc[2], loc[3]);
  fp[1] = make_uint4(loc[4], loc[5], loc[6], loc[7]);
}

// Per-cloud: coord gather (8 independent loads), density/cov/unit vectors.
// Indices in the low 12 bits of the key (j < 4096).
__device__ __forceinline__ void cloud_stats(const float* __restrict__ C, int i,
                                            const uint32_t v[KNN],
                                            float& dsum, float cov[6],
                                            float nx[KNN], float ny[KNN], float nz[KNN]) {
  const float qx = C[3 * i], qy = C[3 * i + 1], qz = C[3 * i + 2];
  float jx[KNN], jy[KNN], jz[KNN];
#pragma unroll
  for (int k = 0; k < KNN; ++k) {
    const int j = (int)(v[k] & 0xFFFu);
    jx[k] = C[3 * j]; jy[k] = C[3 * j + 1]; jz[k] = C[3 * j + 2];
  }
  dsum = 0.f;
#pragma unroll
  for (int m = 0; m < 6; ++m) cov[m] = 0.f;
#pragma unroll
  for (int k = 0; k < KNN; ++k) {
    const float ax = jx[k] - qx, ay = jy[k] - qy, az = jz[k] - qz;
    const float d2 = fmaf(ax, ax, fmaf(ay, ay, az * az));
    const float dist = sqrtf(fmaxf(d2, EPS_F));
    const float inv = 1.0f / fmaxf(dist, EPS_F);
    dsum += dist;
    cov[0] += ax * ax; cov[1] += ay * ay; cov[2] += az * az;
    cov[3] += ax * ay; cov[4] += ax * az; cov[5] += ay * az;
    nx[k] = ax * inv; ny[k] = ay * inv; nz[k] = az * inv;
  }
}

// ---------------------------------------------------------------------------
// loss_k — proven stats/reduction path; reads the per-point top-8 directly.
// ---------------------------------------------------------------------------
__global__ void __launch_bounds__(64, 1)
loss_k(const float* __restrict__ pred, const float* __restrict__ tgt,
       const uint32_t* __restrict__ fin, double* __restrict__ bsum,
       uint32_t* __restrict__ ticket, float* __restrict__ out) {
  const int p = blockIdx.x * 64 + threadIdx.x;   // 0 .. 16383
  const int b = p >> 12;
  const int i = p & (NPTS - 1);

  const float* __restrict__ P = pred + (size_t)b * NPTS * 3;
  const float* __restrict__ T = tgt  + (size_t)b * NPTS * 3;

  uint32_t vp[KNN], vt[KNN];
  {
    const uint4* fp = (const uint4*)(fin + ((size_t)b * NPTS + (size_t)i) * 8);
    const uint4 a0 = fp[0], a1 = fp[1];
    vp[0] = a0.x; vp[1] = a0.y; vp[2] = a0.z; vp[3] = a0.w;
    vp[4] = a1.x; vp[5] = a1.y; vp[6] = a1.z; vp[7] = a1.w;
    const uint4* ft = (const uint4*)(fin + ((size_t)(BATCH + b) * NPTS + (size_t)i) * 8);
    const uint4 b0 = ft[0], b1 = ft[1];
    vt[0] = b0.x; vt[1] = b0.y; vt[2] = b0.z; vt[3] = b0.w;
    vt[4] = b1.x; vt[5] = b1.y; vt[6] = b1.z; vt[7] = b1.w;
  }

  float dsp, dst, pcov[6], tcov[6];
  float pnx[KNN], pny[KNN], pnz[KNN], tnx[KNN], tny[KNN], tnz[KNN];
  cloud_stats(P, i, vp, dsp, pcov, pnx, pny, pnz);
  cloud_stats(T, i, vt, dst, tcov, tnx, tny, tnz);

  float sdot = 0.f;
#pragma unroll
  for (int k = 0; k < KNN; ++k)
    sdot += pnx[k] * tnx[k] + pny[k] * tny[k] + pnz[k] * tnz[k];

  const float densp = dsp * (1.0f / KNN);
  const float denst = dst * (1.0f / KNN);
  float e = (densp - denst) * (densp - denst);

  const float dxx = (pcov[0] - tcov[0]) * (1.0f / KNN);
  const float dyy = (pcov[1] - tcov[1]) * (1.0f / KNN);
  const float dzz = (pcov[2] - tcov[2]) * (1.0f / KNN);
  const float dxy = (pcov[3] - tcov[3]) * (1.0f / KNN);
  const float dxz = (pcov[4] - tcov[4]) * (1.0f / KNN);
  const float dyz = (pcov[5] - tcov[5]) * (1.0f / KNN);
  float cfro = sqrtf(dxx * dxx + dyy * dyy + dzz * dzz
                     + 2.0f * (dxy * dxy + dxz * dxz + dyz * dyz));
  float s = sdot;

#pragma unroll
  for (int off = 32; off > 0; off >>= 1) {
    e    += __shfl_down(e, off);
    s    += __shfl_down(s, off);
    cfro += __shfl_down(cfro, off);
  }

  unsigned rank = 0u;
  if (threadIdx.x == 0) {
    double* d = bsum + 3 * (size_t)blockIdx.x;
    d[0] = (double)e; d[1] = (double)s; d[2] = (double)cfro;
    __threadfence();                       // release
    rank = atomicAdd(ticket, 1u) + 1u;
  }
  rank = __shfl(rank, 0);
  if (rank == (unsigned)NBLK2) {           // last block: whole wave reduces
    __threadfence();                       // acquire
    double ee = 0.0, ss = 0.0, cc = 0.0;
#pragma unroll
    for (int g = 0; g < NBLK2 / 64; ++g) {
      double* d = bsum + 3 * (size_t)(threadIdx.x + 64 * g);
      ee += __hip_atomic_load(&d[0], __ATOMIC_RELAXED, __HIP_MEMORY_SCOPE_AGENT);
      ss += __hip_atomic_load(&d[1], __ATOMIC_RELAXED, __HIP_MEMORY_SCOPE_AGENT);
      cc += __hip_atomic_load(&d[2], __ATOMIC_RELAXED, __HIP_MEMORY_SCOPE_AGENT);
    }
#pragma unroll
    for (int off = 32; off > 0; off >>= 1) {
      ee += __shfl_down(ee, off);
      ss += __shfl_down(ss, off);
      cc += __shfl_down(cc, off);
    }
    if (threadIdx.x == 0) {
      const double BN = (double)BATCH * (double)NPTS;
      out[0] = (float)(ee / BN + 0.5 * (1.0 - ss / (BN * (double)KNN)) + 0.5 * (cc / BN));
    }
  }
}

extern "C" void kernel_launch(void* const* d_in, const int* in_sizes, int n_in,
                              void* d_out, int out_size, void* d_ws, size_t ws_size,
                              hipStream_t stream) {
  const float* pred = (const float*)d_in[0];
  const float* tgt  = (const float*)d_in[1];
  uint32_t* ticket = (uint32_t*)((char*)d_ws + 64);
  double*   bsum   = (double*)((char*)d_ws + 4096);            // 256 x 3 doubles
  uint32_t* fin    = (uint32_t*)((char*)d_ws + 65536);         // 1 MB (8 x 4096 x 8 u32)
  uint32_t* cnt    = (uint32_t*)((char*)d_ws + (2u << 20));    // 1 MB (8 x 32768 u32)
  uint32_t* off    = (uint32_t*)((char*)d_ws + (3u << 20));    // 1 MB (8 x 32768 u32)
  uint32_t* pcs    = (uint32_t*)((char*)d_ws + (4u << 20));    // 128 KB (32768 u32)
  float4*   srt    = (float4*)((char*)d_ws + (5u << 20));      // 512 KB (8 x 4096 f4)

  zero_k<<<256, 256, 0, stream>>>(cnt, ticket);
  count_k<<<(NSET * NPTS) / 256, 256, 0, stream>>>(pred, tgt, cnt, pcs);
  offsets_k<<<NSET, 1024, 0, stream>>>(cnt, off);
  scatter_k<<<(NSET * NPTS) / 256, 256, 0, stream>>>(pred, tgt, off, pcs, srt);
  scan_k<<<(NSET * NPTS) / 64, 64, 0, stream>>>(srt, cnt, off, fin);
  loss_k<<<NBLK2, 64, 0, stream>>>(pred, tgt, fin, bsum, ticket, (float*)d_out);
}

// Round 13
// 148.687 us; speedup vs baseline: 5.4117x; 2.8927x over previous
//
#include <hip/hip_runtime.h>
#include <cstdint>
#include <cstddef>

#define NPTS   4096
#define BATCH  4
#define NSET   (2 * BATCH)     // 8 point sets (2 clouds x 4 batches)
#define KNN    8
#define EPS_F  1e-12f
#define NBLK2  ((BATCH * NPTS) / 64)   // 256 loss blocks

// Spatial grid: 32^3 cells of h=0.3125 over [-5,5]^3 (N(0,1) data:
// densest cell ~8 pts; P(|coord|>5) ~ 6e-7 -> clamped to edge cells).
#define G      32
#define NC3    (G * G * G)     // 32768 cells
#define GLO    -5.0f
#define GH     0.3125f         // 5/16, exact in fp32
#define GINV   3.2f

__device__ __forceinline__ uint32_t u32min(uint32_t a, uint32_t b) { return a < b ? a : b; }
__device__ __forceinline__ uint32_t u32max(uint32_t a, uint32_t b) { return a > b ? a : b; }

// v_med3_u32: for sorted a<=b, med3(a,b,x) == clamp(x,a,b) — one instruction.
__device__ __forceinline__ uint32_t umed3(uint32_t a, uint32_t b, uint32_t c) {
  uint32_t d;
  asm("v_med3_u32 %0, %1, %2, %3" : "=v"(d) : "v"(a), "v"(b), "v"(c));
  return d;
}

// Insert key into ascending D-list, dropping the largest: 1 min + (D-1) med3.
template <int D>
__device__ __forceinline__ void insertD(uint32_t (&loc)[D], uint32_t key) {
  uint32_t prev = loc[0];
  loc[0] = u32min(prev, key);
#pragma unroll
  for (int m = 1; m < D; ++m) {
    const uint32_t cur = loc[m];
    loc[m] = umed3(prev, cur, key);
    prev = cur;
  }
}

// Merge two sorted-ascending 8-lists, keep the smallest 8, sorted (proven).
// Symmetric in its arguments (result = sorted smallest-8 of the union), so
// both lanes of a shfl_xor pair compute the identical list.
__device__ __forceinline__ void merge2(uint32_t A[KNN], const uint32_t B[KNN]) {
  uint32_t t[KNN];
#pragma unroll
  for (int m = 0; m < KNN; ++m) t[m] = u32min(A[m], B[KNN - 1 - m]);
#define CEU(x, y) { uint32_t lo = u32min(t[x], t[y]); uint32_t hi = u32max(t[x], t[y]); t[x] = lo; t[y] = hi; }
  CEU(0,4) CEU(1,5) CEU(2,6) CEU(3,7)
  CEU(0,2) CEU(1,3) CEU(4,6) CEU(5,7)
  CEU(0,1) CEU(2,3) CEU(4,5) CEU(6,7)
#undef CEU
#pragma unroll
  for (int m = 0; m < KNN; ++m) A[m] = t[m];
}

__device__ __forceinline__ int cell1d(float x) {
  int c = (int)floorf((x - GLO) * GINV);
  return c < 0 ? 0 : (c > G - 1 ? G - 1 : c);
}

// ---------------------------------------------------------------------------
// zero_k: clear cell counters (1 MB) + ticket. Runs every launch (re-poison
// safe: graph replays always start from clean counts).
// ---------------------------------------------------------------------------
__global__ void __launch_bounds__(256)
zero_k(uint32_t* __restrict__ cnt, uint32_t* __restrict__ ticket) {
  const int t = blockIdx.x * 256 + threadIdx.x;      // 0..65535
  ((uint4*)cnt)[t] = make_uint4(0u, 0u, 0u, 0u);     // NSET*NC3 u32 = 1 MB
  if (t == 0) *ticket = 0u;
}

// ---------------------------------------------------------------------------
// count_k: per point, atomically grab a slot in its cell; record (cid, slot).
// Slot order is nondeterministic; selection is order-independent (strict
// truncated-d2|j key order), so the final result is deterministic.
// ---------------------------------------------------------------------------
__global__ void __launch_bounds__(256)
count_k(const float* __restrict__ pred, const float* __restrict__ tgt,
        uint32_t* __restrict__ cnt, uint32_t* __restrict__ pcs) {
  const int t = blockIdx.x * 256 + threadIdx.x;      // 0..32767
  const int set = t >> 12, j = t & (NPTS - 1);
  const float* pts = ((set >> 2) ? tgt : pred) + (size_t)(set & 3) * NPTS * 3;
  const float x = pts[3 * j], y = pts[3 * j + 1], z = pts[3 * j + 2];
  const int cid = (cell1d(x) << 10) | (cell1d(y) << 5) | cell1d(z);
  const uint32_t slot = atomicAdd(&cnt[(size_t)set * NC3 + cid], 1u);
  pcs[t] = (uint32_t)cid | (slot << 16);
}

// ---------------------------------------------------------------------------
// offsets_k: exclusive prefix sum cnt -> off, one block per set (proven R11).
// ---------------------------------------------------------------------------
__global__ void __launch_bounds__(1024)
offsets_k(const uint32_t* __restrict__ cnt, uint32_t* __restrict__ off) {
  __shared__ uint32_t sbuf[1024];
  const int set = blockIdx.x, t = threadIdx.x;
  const uint32_t* C = cnt + (size_t)set * NC3 + t * 32;
  uint32_t c[32];
  uint32_t sum = 0;
#pragma unroll
  for (int k = 0; k < 32; ++k) { c[k] = C[k]; sum += c[k]; }
  const uint32_t mysum = sum;
  sbuf[t] = sum;
  __syncthreads();
#pragma unroll
  for (int d = 1; d < 1024; d <<= 1) {
    const uint32_t v = (t >= d) ? sbuf[t - d] : 0u;
    __syncthreads();
    sbuf[t] += v;
    __syncthreads();
  }
  uint32_t run = sbuf[t] - mysum;          // exclusive offset of this thread
  uint32_t* O = off + (size_t)set * NC3 + t * 32;
#pragma unroll
  for (int k = 0; k < 32; ++k) { O[k] = run; run += c[k]; }
}

// ---------------------------------------------------------------------------
// scatter_k: write each point as float4(x,y,z, bitcast j) into cell-sorted
// CSR order: pos = off[cid] + slot.
// ---------------------------------------------------------------------------
__global__ void __launch_bounds__(256)
scatter_k(const float* __restrict__ pred, const float* __restrict__ tgt,
          const uint32_t* __restrict__ off, const uint32_t* __restrict__ pcs,
          float4* __restrict__ srt) {
  const int t = blockIdx.x * 256 + threadIdx.x;      // 0..32767
  const int set = t >> 12, j = t & (NPTS - 1);
  const float* pts = ((set >> 2) ? tgt : pred) + (size_t)(set & 3) * NPTS * 3;
  const uint32_t cs = pcs[t];
  const uint32_t cid = cs & 0xFFFFu, slot = cs >> 16;
  const uint32_t pos = off[(size_t)set * NC3 + cid] + slot;
  srt[(size_t)set * NPTS + pos] =
      make_float4(pts[3 * j], pts[3 * j + 1], pts[3 * j + 2], __uint_as_float((uint32_t)j));
}

// ---------------------------------------------------------------------------
// scan_k: ONE WAVE PER POINT. 32768 waves (R12 BUG: launched 512 blocks for
// a 4-wave/block decomposition -> only 1/16 of points computed; fin held
// poison -> absmax 4.76. Fix: 8192 blocks). Per phase (box of Chebyshev
// radius L): per X-plane, cells (X,ylo,zlo)..(X,yhi,zhi) are ONE contiguous
// CSR segment (z-gap cells over-scanned — extra real candidates never
// corrupt an exact top-8); 64 lanes stream coalesced, private top-8 each;
// 6-step shfl_xor butterfly of merge2 -> identical global top-8 in every
// lane (symmetric merge, dup-free partition). Face-distance guarantee
// (clamped face = inf) decides expansion; failing points re-scan the larger
// box from scratch (phase-local lists -> dup-safe, exact).
// Key/truncation/tie/self-drop semantics identical to all proven rounds.
// ---------------------------------------------------------------------------
__global__ void __launch_bounds__(256)
scan_k(const float4* __restrict__ srt, const uint32_t* __restrict__ cnt,
       const uint32_t* __restrict__ off, uint32_t* __restrict__ fin) {
  const int w = blockIdx.x * 4 + (threadIdx.x >> 6);  // wave id: 0..32767
  const int lane = threadIdx.x & 63;
  const int set = w >> 12, r = w & (NPTS - 1);        // r = sorted rank
  const float4* __restrict__ S = srt + (size_t)set * NPTS;
  const uint32_t* __restrict__ C = cnt + (size_t)set * NC3;
  const uint32_t* __restrict__ O = off + (size_t)set * NC3;

  const float4 q = S[r];
  const float px = q.x, py = q.y, pz = q.z;
  const uint32_t iq = __float_as_uint(q.w);           // original index
  const int cx = cell1d(px), cy = cell1d(py), cz = cell1d(pz);

  uint32_t M[KNN];
  int L = 1;
  while (true) {
    const int xlo = cx - L > 0 ? cx - L : 0, xhi = cx + L < G - 1 ? cx + L : G - 1;
    const int ylo = cy - L > 0 ? cy - L : 0, yhi = cy + L < G - 1 ? cy + L : G - 1;
    const int zlo = cz - L > 0 ? cz - L : 0, zhi = cz + L < G - 1 ? cz + L : G - 1;

    uint32_t loc[KNN];
#pragma unroll
    for (int k = 0; k < KNN; ++k) loc[k] = 0xFFFFFFFFu;

    for (int X = xlo; X <= xhi; ++X) {
      const uint32_t s = O[(X << 10) | (ylo << 5) | zlo];
      const int chi = (X << 10) | (yhi << 5) | zhi;
      const uint32_t e = O[chi] + C[chi];
      for (uint32_t p = s + (uint32_t)lane; p < e; p += 64u) {
        const float4 c = S[p];
        const float dx = px - c.x, dy = py - c.y, dz = pz - c.z;
        const float d2 = fmaf(dx, dx, fmaf(dy, dy, dz * dz));
        const uint32_t j = __float_as_uint(c.w);
        uint32_t key = (__float_as_uint(d2) & 0xFFFFF000u) | j;
        key = (j == iq) ? 0xFFFFFFFFu : key;
        insertD<KNN>(loc, key);
      }
    }

    // Butterfly merge: every lane ends with the identical global top-8.
#pragma unroll
    for (int st = 1; st < 64; st <<= 1) {
      uint32_t oth[KNN];
#pragma unroll
      for (int m = 0; m < KNN; ++m) oth[m] = (uint32_t)__shfl_xor((int)loc[m], st);
      merge2(loc, oth);
    }
#pragma unroll
    for (int m = 0; m < KNN; ++m) M[m] = loc[m];

    // Coverage guarantee for the scanned box [c-L, c+L]^3 (clamped = inf).
    const float glx = (cx - L <= 0)     ? 1e30f : px - (GLO + (float)(cx - L) * GH);
    const float ghx = (cx + L >= G - 1) ? 1e30f : (GLO + (float)(cx + L + 1) * GH) - px;
    const float gly = (cy - L <= 0)     ? 1e30f : py - (GLO + (float)(cy - L) * GH);
    const float ghy = (cy + L >= G - 1) ? 1e30f : (GLO + (float)(cy + L + 1) * GH) - py;
    const float glz = (cz - L <= 0)     ? 1e30f : pz - (GLO + (float)(cz - L) * GH);
    const float ghz = (cz + L >= G - 1) ? 1e30f : (GLO + (float)(cz + L + 1) * GH) - pz;
    const float g = fminf(fminf(fminf(glx, ghx), fminf(gly, ghy)), fminf(glz, ghz));
    const float g2 = g * g;
    const bool have8 = (M[KNN - 1] != 0xFFFFFFFFu);
    const float d8u = __uint_as_float((M[KNN - 1] & 0xFFFFF000u) + 0x1000u);
    if (have8 && d8u <= g2) break;
    const bool allx = (cx - L <= 0) && (cx + L >= G - 1);
    const bool ally = (cy - L <= 0) && (cy + L >= G - 1);
    const bool allz = (cz - L <= 0) && (cz + L >= G - 1);
    if (allx && ally && allz) break;   // whole grid scanned
    if (L >= G) break;                 // hard safety stop
    ++L;
  }

  if (lane == 0) {
    uint4* fp = (uint4*)(fin + ((size_t)set * NPTS + (size_t)iq) * 8);
    fp[0] = make_uint4(M[0], M[1], M[2], M[3]);
    fp[1] = make_uint4(M[4], M[5], M[6], M[7]);
  }
}

// Per-cloud: coord gather (8 independent loads), density/cov/unit vectors.
// Indices in the low 12 bits of the key (j < 4096).
__device__ __forceinline__ void cloud_stats(const float* __restrict__ C, int i,
                                            const uint32_t v[KNN],
                                            float& dsum, float cov[6],
                                            float nx[KNN], float ny[KNN], float nz[KNN]) {
  const float qx = C[3 * i], qy = C[3 * i + 1], qz = C[3 * i + 2];
  float jx[KNN], jy[KNN], jz[KNN];
#pragma unroll
  for (int k = 0; k < KNN; ++k) {
    const int j = (int)(v[k] & 0xFFFu);
    jx[k] = C[3 * j]; jy[k] = C[3 * j + 1]; jz[k] = C[3 * j + 2];
  }
  dsum = 0.f;
#pragma unroll
  for (int m = 0; m < 6; ++m) cov[m] = 0.f;
#pragma unroll
  for (int k = 0; k < KNN; ++k) {
    const float ax = jx[k] - qx, ay = jy[k] - qy, az = jz[k] - qz;
    const float d2 = fmaf(ax, ax, fmaf(ay, ay, az * az));
    const float dist = sqrtf(fmaxf(d2, EPS_F));
    const float inv = 1.0f / fmaxf(dist, EPS_F);
    dsum += dist;
    cov[0] += ax * ax; cov[1] += ay * ay; cov[2] += az * az;
    cov[3] += ax * ay; cov[4] += ax * az; cov[5] += ay * az;
    nx[k] = ax * inv; ny[k] = ay * inv; nz[k] = az * inv;
  }
}

// ---------------------------------------------------------------------------
// loss_k — proven stats/reduction path; reads the per-point top-8 directly.
// ---------------------------------------------------------------------------
__global__ void __launch_bounds__(64, 1)
loss_k(const float* __restrict__ pred, const float* __restrict__ tgt,
       const uint32_t* __restrict__ fin, double* __restrict__ bsum,
       uint32_t* __restrict__ ticket, float* __restrict__ out) {
  const int p = blockIdx.x * 64 + threadIdx.x;   // 0 .. 16383
  const int b = p >> 12;
  const int i = p & (NPTS - 1);

  const float* __restrict__ P = pred + (size_t)b * NPTS * 3;
  const float* __restrict__ T = tgt  + (size_t)b * NPTS * 3;

  uint32_t vp[KNN], vt[KNN];
  {
    const uint4* fp = (const uint4*)(fin + ((size_t)b * NPTS + (size_t)i) * 8);
    const uint4 a0 = fp[0], a1 = fp[1];
    vp[0] = a0.x; vp[1] = a0.y; vp[2] = a0.z; vp[3] = a0.w;
    vp[4] = a1.x; vp[5] = a1.y; vp[6] = a1.z; vp[7] = a1.w;
    const uint4* ft = (const uint4*)(fin + ((size_t)(BATCH + b) * NPTS + (size_t)i) * 8);
    const uint4 b0 = ft[0], b1 = ft[1];
    vt[0] = b0.x; vt[1] = b0.y; vt[2] = b0.z; vt[3] = b0.w;
    vt[4] = b1.x; vt[5] = b1.y; vt[6] = b1.z; vt[7] = b1.w;
  }

  float dsp, dst, pcov[6], tcov[6];
  float pnx[KNN], pny[KNN], pnz[KNN], tnx[KNN], tny[KNN], tnz[KNN];
  cloud_stats(P, i, vp, dsp, pcov, pnx, pny, pnz);
  cloud_stats(T, i, vt, dst, tcov, tnx, tny, tnz);

  float sdot = 0.f;
#pragma unroll
  for (int k = 0; k < KNN; ++k)
    sdot += pnx[k] * tnx[k] + pny[k] * tny[k] + pnz[k] * tnz[k];

  const float densp = dsp * (1.0f / KNN);
  const float denst = dst * (1.0f / KNN);
  float e = (densp - denst) * (densp - denst);

  const float dxx = (pcov[0] - tcov[0]) * (1.0f / KNN);
  const float dyy = (pcov[1] - tcov[1]) * (1.0f / KNN);
  const float dzz = (pcov[2] - tcov[2]) * (1.0f / KNN);
  const float dxy = (pcov[3] - tcov[3]) * (1.0f / KNN);
  const float dxz = (pcov[4] - tcov[4]) * (1.0f / KNN);
  const float dyz = (pcov[5] - tcov[5]) * (1.0f / KNN);
  float cfro = sqrtf(dxx * dxx + dyy * dyy + dzz * dzz
                     + 2.0f * (dxy * dxy + dxz * dxz + dyz * dyz));
  float s = sdot;

#pragma unroll
  for (int off = 32; off > 0; off >>= 1) {
    e    += __shfl_down(e, off);
    s    += __shfl_down(s, off);
    cfro += __shfl_down(cfro, off);
  }

  unsigned rank = 0u;
  if (threadIdx.x == 0) {
    double* d = bsum + 3 * (size_t)blockIdx.x;
    d[0] = (double)e; d[1] = (double)s; d[2] = (double)cfro;
    __threadfence();                       // release
    rank = atomicAdd(ticket, 1u) + 1u;
  }
  rank = __shfl(rank, 0);
  if (rank == (unsigned)NBLK2) {           // last block: whole wave reduces
    __threadfence();                       // acquire
    double ee = 0.0, ss = 0.0, cc = 0.0;
#pragma unroll
    for (int g = 0; g < NBLK2 / 64; ++g) {
      double* d = bsum + 3 * (size_t)(threadIdx.x + 64 * g);
      ee += __hip_atomic_load(&d[0], __ATOMIC_RELAXED, __HIP_MEMORY_SCOPE_AGENT);
      ss += __hip_atomic_load(&d[1], __ATOMIC_RELAXED, __HIP_MEMORY_SCOPE_AGENT);
      cc += __hip_atomic_load(&d[2], __ATOMIC_RELAXED, __HIP_MEMORY_SCOPE_AGENT);
    }
#pragma unroll
    for (int off = 32; off > 0; off >>= 1) {
      ee += __shfl_down(ee, off);
      ss += __shfl_down(ss, off);
      cc += __shfl_down(cc, off);
    }
    if (threadIdx.x == 0) {
      const double BN = (double)BATCH * (double)NPTS;
      out[0] = (float)(ee / BN + 0.5 * (1.0 - ss / (BN * (double)KNN)) + 0.5 * (cc / BN));
    }
  }
}

extern "C" void kernel_launch(void* const* d_in, const int* in_sizes, int n_in,
                              void* d_out, int out_size, void* d_ws, size_t ws_size,
                              hipStream_t stream) {
  const float* pred = (const float*)d_in[0];
  const float* tgt  = (const float*)d_in[1];
  uint32_t* ticket = (uint32_t*)((char*)d_ws + 64);
  double*   bsum   = (double*)((char*)d_ws + 4096);            // 256 x 3 doubles
  uint32_t* fin    = (uint32_t*)((char*)d_ws + 65536);         // 1 MB (8 x 4096 x 8 u32)
  uint32_t* cnt    = (uint32_t*)((char*)d_ws + (2u << 20));    // 1 MB (8 x 32768 u32)
  uint32_t* off    = (uint32_t*)((char*)d_ws + (3u << 20));    // 1 MB (8 x 32768 u32)
  uint32_t* pcs    = (uint32_t*)((char*)d_ws + (4u << 20));    // 128 KB (32768 u32)
  float4*   srt    = (float4*)((char*)d_ws + (5u << 20));      // 512 KB (8 x 4096 f4)

  zero_k<<<256, 256, 0, stream>>>(cnt, ticket);
  count_k<<<(NSET * NPTS) / 256, 256, 0, stream>>>(pred, tgt, cnt, pcs);
  offsets_k<<<NSET, 1024, 0, stream>>>(cnt, off);
  scatter_k<<<(NSET * NPTS) / 256, 256, 0, stream>>>(pred, tgt, off, pcs, srt);
  scan_k<<<(NSET * NPTS) / 4, 256, 0, stream>>>(srt, cnt, off, fin);  // 8192 blocks = 32768 waves
  loss_k<<<NBLK2, 64, 0, stream>>>(pred, tgt, fin, bsum, ticket, (float*)d_out);
}